// Round 10
// baseline (92.809 us; speedup 1.0000x reference)
//
#include <hip/hip_runtime.h>
#include <hip/hip_bf16.h>
#include <cstdint>

// B=2048, C=256, P=15, channels=512, groups=4 (128 ch each)
// r10: 1 batch/block, 2048 blocks, 16.6 KB LDS, launch_bounds(256,8)
//  -> 8 blocks/CU (32 waves/CU) to attack the latency-bound profile seen in r9.
// MFMA stays 32x32 with A-rows 16..31 fed exact zeros (stats unaffected).
#define EPS_ 1e-5f
#define NVALID_F 30720.0f

typedef __bf16 bf16x8 __attribute__((ext_vector_type(8)));
typedef float f32x16 __attribute__((ext_vector_type(16)));
typedef float f32x4 __attribute__((ext_vector_type(4)));
typedef unsigned short u16x8 __attribute__((ext_vector_type(8)));

__device__ __forceinline__ unsigned short f2bf(float f) {
  unsigned u = __float_as_uint(f);
  u += 0x7FFFu + ((u >> 16) & 1u);   // RNE
  return (unsigned short)(u >> 16);
}
__device__ __forceinline__ float bf2f(unsigned short h) {
  return __uint_as_float((unsigned)h << 16);
}

// ---- prologue: conv_w f32 [4][128][128] -> bf16 MFMA B-fragments (r7-proven) ----
// Wf[g][mt][ks][lane][j] = w[g][o=mt*32+(lane&31)][i=ks*16+(lane>>5)*8+j]
__global__ void k_wprep(const float* __restrict__ w, unsigned short* __restrict__ wf) {
  int q = blockIdx.x * 256 + threadIdx.x;  // 0..8191
  int l = q & 63, ks = (q >> 6) & 7, mt = (q >> 9) & 3, g = q >> 11;
  int o = mt * 32 + (l & 31);
  int i = ks * 16 + (l >> 5) * 8;
  const float* src = w + ((size_t)(g * 128 + o) * 128 + i);
  u16x8 v;
#pragma unroll
  for (int j = 0; j < 8; ++j) v[j] = f2bf(src[j]);
  *(u16x8*)(wf + (size_t)q * 8) = v;
}

// Build Y (xs|tmp) for ONE batch into Yt[16*520]; x staged through Yt union.
__device__ __forceinline__ void build_Y1(const float* __restrict__ x, int b, int t,
                                         unsigned short* __restrict__ Yt) {
  {
    const f32x4* src = (const f32x4*)(x + (size_t)b * 3840);
    f32x4* dst = (f32x4*)Yt;
    for (int q = t; q < 960; q += 256) dst[q] = src[q];   // 15360 B <= 16640 B
  }
  __syncthreads();
  float v[15];
  {
    const float* xsf = (const float*)Yt;
#pragma unroll
    for (int p = 0; p < 15; ++p) v[p] = xsf[t * 15 + p];
  }
  __syncthreads();   // all reads done before Yt overwrite
  float pm[5];
#pragma unroll
  for (int q = 0; q < 5; ++q) pm[q] = fmaxf(fmaxf(v[3 * q], v[3 * q + 1]), v[3 * q + 2]);
  float mq[5];
  mq[0] = fmaxf(fmaxf(pm[1], pm[2]), fmaxf(pm[3], pm[4]));
  mq[1] = fmaxf(fmaxf(pm[0], pm[2]), fmaxf(pm[3], pm[4]));
  mq[2] = fmaxf(fmaxf(pm[0], pm[1]), fmaxf(pm[3], pm[4]));
  mq[3] = fmaxf(fmaxf(pm[0], pm[1]), fmaxf(pm[2], pm[4]));
  mq[4] = fmaxf(fmaxf(pm[0], pm[1]), fmaxf(pm[2], pm[3]));
#pragma unroll
  for (int p = 0; p < 15; ++p) {
    Yt[p * 520 + t] = f2bf(v[p]);                  // xs -> ch 0..255
    Yt[p * 520 + 256 + t] = f2bf(mq[p / 3] - v[p]); // tmp -> ch 256..511
  }
  Yt[15 * 520 + t] = 0;        // pad row: exact 0 (stats unaffected)
  Yt[15 * 520 + 256 + t] = 0;
}

// ---- pass 1: GEMM (rows 16..31 zero), per-block (s,s2) partials ----
__global__ __launch_bounds__(256, 8) void k_pass1(const float* __restrict__ x,
                                                  const unsigned short* __restrict__ wf,
                                                  float2* __restrict__ Part) {
  __shared__ __align__(16) unsigned short Yt[16 * 520];
  const int t = threadIdx.x;
  build_Y1(x, blockIdx.x, t, Yt);
  __syncthreads();

  const int lane = t & 63, g = t >> 6;
  const int l31 = lane & 31, lh = lane >> 5;
  const bf16x8* Wfv = (const bf16x8*)wf;

  union ZU { u16x8 u; bf16x8 b; };
  ZU zz; zz.u = (u16x8){0, 0, 0, 0, 0, 0, 0, 0};
  const bf16x8 zero8 = zz.b;

  bf16x8 bfr[8];
  const unsigned short* yrow = &Yt[(l31 & 15) * 520 + g * 128 + lh * 8];
#pragma unroll
  for (int ks = 0; ks < 8; ++ks) {
    bf16x8 ld = *(const bf16x8*)(yrow + ks * 16);
    bfr[ks] = (l31 < 16) ? ld : zero8;   // A-rows 16..31 = exact 0
  }

  for (int mt = 0; mt < 4; ++mt) {
    bf16x8 wr[8];
#pragma unroll
    for (int ks = 0; ks < 8; ++ks)
      wr[ks] = Wfv[(size_t)((g * 4 + mt) * 8 + ks) * 64 + lane];
    f32x16 acc;
#pragma unroll
    for (int r = 0; r < 16; ++r) acc[r] = 0.f;
#pragma unroll
    for (int ks = 0; ks < 8; ++ks)
      acc = __builtin_amdgcn_mfma_f32_32x32x16_bf16(bfr[ks], wr[ks], acc, 0, 0, 0);
    float s = 0.f, s2 = 0.f;
#pragma unroll
    for (int r = 0; r < 16; ++r) { float vv = acc[r]; s += vv; s2 = fmaf(vv, vv, s2); }
    s += __shfl_xor(s, 32, 64);
    s2 += __shfl_xor(s2, 32, 64);
    const int ch = g * 128 + mt * 32 + l31;
    if (lane < 32) Part[(size_t)blockIdx.x * 512 + ch] = make_float2(s, s2);
  }
}

// ---- stats: 64 blocks x 8 ch; dense 64B-line reads over 2048 partial rows ----
__global__ void k_stats(const float2* __restrict__ Part,
                        const float* __restrict__ gamma, const float* __restrict__ beta,
                        float2* __restrict__ AB) {
  const int t = threadIdx.x;
  const int chb = blockIdx.x * 8;
  const int c = t & 7, r0 = t >> 3;
  float s = 0.f, s2 = 0.f;
  for (int k = 0; k < 64; ++k) {
    float2 vv = Part[(size_t)(r0 + 32 * k) * 512 + chb + c];
    s += vv.x; s2 += vv.y;
  }
  s += __shfl_xor(s, 8, 64);  s2 += __shfl_xor(s2, 8, 64);
  s += __shfl_xor(s, 16, 64); s2 += __shfl_xor(s2, 16, 64);
  s += __shfl_xor(s, 32, 64); s2 += __shfl_xor(s2, 32, 64);
  __shared__ float2 red[4][8];
  if ((t & 63) < 8) red[t >> 6][c] = make_float2(s, s2);
  __syncthreads();
  if (t < 8) {
    float S = 0.f, S2 = 0.f;
#pragma unroll
    for (int w = 0; w < 4; ++w) { S += red[w][t].x; S2 += red[w][t].y; }
    const float inv = 1.f / NVALID_F;
    float mean = S * inv;
    float var = fmaxf(S2 * inv - mean * mean, 0.f);
    float a = gamma[chb + t] * rsqrtf(var + EPS_);
    AB[chb + t] = make_float2(a, beta[chb + t] - mean * a);
  }
}

// ---- pass 2: recompute GEMM, z-tile in LDS, finalize (AB read direct) ----
__global__ __launch_bounds__(256, 8) void k_pass2(const float* __restrict__ x,
                                                  const unsigned short* __restrict__ wf,
                                                  const float2* __restrict__ AB,
                                                  float* __restrict__ out) {
  __shared__ __align__(16) unsigned short Yt[16 * 520];
  const int t = threadIdx.x;
  build_Y1(x, blockIdx.x, t, Yt);
  __syncthreads();

  {
    const int lane = t & 63, g = t >> 6;
    const int l31 = lane & 31, lh = lane >> 5;
    const bf16x8* Wfv = (const bf16x8*)wf;

    union ZU { u16x8 u; bf16x8 b; };
    ZU zz; zz.u = (u16x8){0, 0, 0, 0, 0, 0, 0, 0};
    const bf16x8 zero8 = zz.b;

    bf16x8 bfr[8];
    const unsigned short* yrow = &Yt[(l31 & 15) * 520 + g * 128 + lh * 8];
#pragma unroll
    for (int ks = 0; ks < 8; ++ks) {
      bf16x8 ld = *(const bf16x8*)(yrow + ks * 16);
      bfr[ks] = (l31 < 16) ? ld : zero8;
    }

    // wave g reads+writes only cols [g*128, g*128+128): no inter-wave hazard
    for (int mt = 0; mt < 4; ++mt) {
      bf16x8 wr[8];
#pragma unroll
      for (int ks = 0; ks < 8; ++ks)
        wr[ks] = Wfv[(size_t)((g * 4 + mt) * 8 + ks) * 64 + lane];
      f32x16 acc;
#pragma unroll
      for (int r = 0; r < 16; ++r) acc[r] = 0.f;
#pragma unroll
      for (int ks = 0; ks < 8; ++ks)
        acc = __builtin_amdgcn_mfma_f32_32x32x16_bf16(bfr[ks], wr[ks], acc, 0, 0, 0);
      const int ch = g * 128 + mt * 32 + l31;
#pragma unroll
      for (int r = 0; r < 16; ++r) {
        int row = (r & 3) + 8 * (r >> 2) + 4 * lh;
        if (row < 16) Yt[row * 520 + ch] = f2bf(acc[r]);   // row 15 = pad, never read
      }
    }
  }
  __syncthreads();   // z-tile visible to all waves

  float2* slab = (float2*)(out + (size_t)blockIdx.x * 7680);
#pragma unroll 5
  for (int k = 0; k < 15; ++k) {
    int e0 = k * 512 + 2 * t;
    int ch0 = e0 / 15, p0 = e0 - ch0 * 15;
    int e1 = e0 + 1;
    int ch1 = e1 / 15, p1 = e1 - ch1 * 15;
    float2 ab0 = AB[ch0];
    float2 ab1 = AB[ch1];
    float f0 = bf2f(Yt[p0 * 520 + ch0]);
    float f1 = bf2f(Yt[p1 * 520 + ch1]);
    slab[k * 256 + t] = make_float2(
        fmaxf(fmaf(f0, ab0.x, ab0.y), 0.f),
        fmaxf(fmaf(f1, ab1.x, ab1.y), 0.f));
  }
}

extern "C" void kernel_launch(void* const* d_in, const int* in_sizes, int n_in,
                              void* d_out, int out_size, void* d_ws, size_t ws_size,
                              hipStream_t stream) {
  const float* x = (const float*)d_in[0];
  const float* cw = (const float*)d_in[1];
  // d_in[2] = conv_b: cancelled exactly by training-mode BN -> unused
  const float* gamma = (const float*)d_in[3];
  const float* beta = (const float*)d_in[4];

  unsigned short* wf = (unsigned short*)d_ws;             // 8192*8 bf16 = 128 KB
  float2* Part = (float2*)(wf + 65536);                   // 2048*512 float2 = 8 MB
  float2* AB = Part + (size_t)2048 * 512;                 // 512 float2 = 4 KB

  hipLaunchKernelGGL(k_wprep, dim3(32), dim3(256), 0, stream, cw, wf);
  hipLaunchKernelGGL(k_pass1, dim3(2048), dim3(256), 0, stream, x, wf, Part);
  hipLaunchKernelGGL(k_stats, dim3(64), dim3(256), 0, stream, Part, gamma, beta, AB);
  hipLaunchKernelGGL(k_pass2, dim3(2048), dim3(256), 0, stream, x, wf, AB, (float*)d_out);
}

// Round 11
// 62.650 us; speedup vs baseline: 1.4814x; 1.4814x over previous
//
#include <hip/hip_runtime.h>
#include <hip/hip_bf16.h>
#include <cstdint>

// B=2048, C=256, P=15, channels=512, groups=4 (128 ch each)
// r11: 16x16x32 MFMA redesign. 1 batch/block, 2048 blocks, 16.6 KB LDS,
// launch_bounds(256,8) with a ~50-VGPR working set (r10 spilled at 32x32).
#define EPS_ 1e-5f
#define NVALID_F 30720.0f

typedef __bf16 bf16x8 __attribute__((ext_vector_type(8)));
typedef float f32x4 __attribute__((ext_vector_type(4)));
typedef unsigned short u16x8 __attribute__((ext_vector_type(8)));

__device__ __forceinline__ unsigned short f2bf(float f) {
  unsigned u = __float_as_uint(f);
  u += 0x7FFFu + ((u >> 16) & 1u);   // RNE
  return (unsigned short)(u >> 16);
}
__device__ __forceinline__ float bf2f(unsigned short h) {
  return __uint_as_float((unsigned)h << 16);
}

// ---- prologue: conv_w f32 [4][128][128] -> bf16 16x16x32 B-fragments ----
// Wf[g][ct][ks][lane][j] = w[g][o=ct*16+(lane&15)][i=ks*32+(lane>>4)*8+j]
__global__ void k_wprep(const float* __restrict__ w, unsigned short* __restrict__ wf) {
  int q = blockIdx.x * 256 + threadIdx.x;  // 0..8191
  int lane = q & 63, ks = (q >> 6) & 3, ct = (q >> 8) & 7, g = q >> 11;
  int o = ct * 16 + (lane & 15);
  int i = ks * 32 + (lane >> 4) * 8;
  const float* src = w + ((size_t)(g * 128 + o) * 128 + i);
  u16x8 v;
#pragma unroll
  for (int j = 0; j < 8; ++j) v[j] = f2bf(src[j]);
  *(u16x8*)(wf + (size_t)q * 8) = v;
}

// Build Y (xs|tmp) for ONE batch into Yt[16*520]; x staged through Yt union.
__device__ __forceinline__ void build_Y1(const float* __restrict__ x, int b, int t,
                                         unsigned short* __restrict__ Yt) {
  {
    const f32x4* src = (const f32x4*)(x + (size_t)b * 3840);
    f32x4* dst = (f32x4*)Yt;
    for (int q = t; q < 960; q += 256) dst[q] = src[q];   // 15360 B <= 16640 B
  }
  __syncthreads();
  float v[15];
  {
    const float* xsf = (const float*)Yt;
#pragma unroll
    for (int p = 0; p < 15; ++p) v[p] = xsf[t * 15 + p];
  }
  __syncthreads();   // all reads done before Yt overwrite
  float pm[5];
#pragma unroll
  for (int q = 0; q < 5; ++q) pm[q] = fmaxf(fmaxf(v[3 * q], v[3 * q + 1]), v[3 * q + 2]);
  float mq[5];
  mq[0] = fmaxf(fmaxf(pm[1], pm[2]), fmaxf(pm[3], pm[4]));
  mq[1] = fmaxf(fmaxf(pm[0], pm[2]), fmaxf(pm[3], pm[4]));
  mq[2] = fmaxf(fmaxf(pm[0], pm[1]), fmaxf(pm[3], pm[4]));
  mq[3] = fmaxf(fmaxf(pm[0], pm[1]), fmaxf(pm[2], pm[4]));
  mq[4] = fmaxf(fmaxf(pm[0], pm[1]), fmaxf(pm[2], pm[3]));
#pragma unroll
  for (int p = 0; p < 15; ++p) {
    Yt[p * 520 + t] = f2bf(v[p]);                   // xs -> ch 0..255
    Yt[p * 520 + 256 + t] = f2bf(mq[p / 3] - v[p]); // tmp -> ch 256..511
  }
  Yt[15 * 520 + t] = 0;        // pad row: exact 0 (z row 15 = 0 -> stats unaffected)
  Yt[15 * 520 + 256 + t] = 0;
}

// ---- pass 1: 16x16 GEMM, per-block (s,s2) partials ----
__global__ __launch_bounds__(256, 8) void k_pass1(const float* __restrict__ x,
                                                  const unsigned short* __restrict__ wf,
                                                  float2* __restrict__ Part) {
  __shared__ __align__(16) unsigned short Yt[16 * 520];
  const int t = threadIdx.x;
  build_Y1(x, blockIdx.x, t, Yt);
  __syncthreads();

  const int lane = t & 63, g = t >> 6;
  const int r16 = lane & 15, q4 = lane >> 4;
  const bf16x8* Wfv = (const bf16x8*)wf;

  // A-frags (Y): row=r16 (n), k = ks*32 + q4*8 + j  -- 16 VGPR, loaded once
  bf16x8 afr[4];
  const unsigned short* yrow = &Yt[r16 * 520 + g * 128 + q4 * 8];
#pragma unroll
  for (int ks = 0; ks < 4; ++ks)
    afr[ks] = *(const bf16x8*)(yrow + ks * 32);

  for (int ct = 0; ct < 8; ++ct) {
    bf16x8 wr[4];
#pragma unroll
    for (int ks = 0; ks < 4; ++ks)
      wr[ks] = Wfv[(size_t)(((g * 8 + ct) * 4 + ks) * 64) + lane];
    f32x4 acc = {0.f, 0.f, 0.f, 0.f};
#pragma unroll
    for (int ks = 0; ks < 4; ++ks)
      acc = __builtin_amdgcn_mfma_f32_16x16x32_bf16(afr[ks], wr[ks], acc, 0, 0, 0);
    // lane holds z[rows q4*4..q4*4+3][ch=ct*16+r16]; sum rows across q4 groups
    float s = acc[0] + acc[1] + acc[2] + acc[3];
    float s2 = fmaf(acc[0], acc[0],
               fmaf(acc[1], acc[1], fmaf(acc[2], acc[2], acc[3] * acc[3])));
    s += __shfl_xor(s, 16, 64); s2 += __shfl_xor(s2, 16, 64);
    s += __shfl_xor(s, 32, 64); s2 += __shfl_xor(s2, 32, 64);
    if (lane < 16)
      Part[(size_t)blockIdx.x * 512 + g * 128 + ct * 16 + lane] = make_float2(s, s2);
  }
}

// ---- stats: 64 blocks x 8 ch; dense 64B-line reads over 2048 partial rows ----
__global__ void k_stats(const float2* __restrict__ Part,
                        const float* __restrict__ gamma, const float* __restrict__ beta,
                        float2* __restrict__ AB) {
  const int t = threadIdx.x;
  const int chb = blockIdx.x * 8;
  const int c = t & 7, r0 = t >> 3;
  float s = 0.f, s2 = 0.f;
  for (int k = 0; k < 64; ++k) {
    float2 vv = Part[(size_t)(r0 + 32 * k) * 512 + chb + c];
    s += vv.x; s2 += vv.y;
  }
  s += __shfl_xor(s, 8, 64);  s2 += __shfl_xor(s2, 8, 64);
  s += __shfl_xor(s, 16, 64); s2 += __shfl_xor(s2, 16, 64);
  s += __shfl_xor(s, 32, 64); s2 += __shfl_xor(s2, 32, 64);
  __shared__ float2 red[4][8];
  if ((t & 63) < 8) red[t >> 6][c] = make_float2(s, s2);
  __syncthreads();
  if (t < 8) {
    float S = 0.f, S2 = 0.f;
#pragma unroll
    for (int w = 0; w < 4; ++w) { S += red[w][t].x; S2 += red[w][t].y; }
    const float inv = 1.f / NVALID_F;
    float mean = S * inv;
    float var = fmaxf(S2 * inv - mean * mean, 0.f);
    float a = gamma[chb + t] * rsqrtf(var + EPS_);
    AB[chb + t] = make_float2(a, beta[chb + t] - mean * a);
  }
}

// ---- pass 2: recompute 16x16 GEMM, z-tile in LDS, finalize (AB direct) ----
__global__ __launch_bounds__(256, 8) void k_pass2(const float* __restrict__ x,
                                                  const unsigned short* __restrict__ wf,
                                                  const float2* __restrict__ AB,
                                                  float* __restrict__ out) {
  __shared__ __align__(16) unsigned short Yt[16 * 520];
  const int t = threadIdx.x;
  build_Y1(x, blockIdx.x, t, Yt);
  __syncthreads();

  {
    const int lane = t & 63, g = t >> 6;
    const int r16 = lane & 15, q4 = lane >> 4;
    const bf16x8* Wfv = (const bf16x8*)wf;

    bf16x8 afr[4];
    const unsigned short* yrow = &Yt[r16 * 520 + g * 128 + q4 * 8];
#pragma unroll
    for (int ks = 0; ks < 4; ++ks)
      afr[ks] = *(const bf16x8*)(yrow + ks * 32);
    // afr reads complete (in-order DS) before this wave's writes below;
    // wave g touches only cols [g*128, g*128+128): no inter-wave hazard.

    for (int ct = 0; ct < 8; ++ct) {
      bf16x8 wr[4];
#pragma unroll
      for (int ks = 0; ks < 4; ++ks)
        wr[ks] = Wfv[(size_t)(((g * 8 + ct) * 4 + ks) * 64) + lane];
      f32x4 acc = {0.f, 0.f, 0.f, 0.f};
#pragma unroll
      for (int ks = 0; ks < 4; ++ks)
        acc = __builtin_amdgcn_mfma_f32_16x16x32_bf16(afr[ks], wr[ks], acc, 0, 0, 0);
      const int ch = g * 128 + ct * 16 + r16;
#pragma unroll
      for (int r = 0; r < 4; ++r) {
        int row = q4 * 4 + r;
        Yt[row * 520 + ch] = f2bf(acc[r]);   // row 15 = pad, never read
      }
    }
  }
  __syncthreads();   // z-tile visible to all waves

  float2* slab = (float2*)(out + (size_t)blockIdx.x * 7680);
#pragma unroll 5
  for (int k = 0; k < 15; ++k) {
    int e0 = k * 512 + 2 * t;
    int ch0 = e0 / 15, p0 = e0 - ch0 * 15;
    int e1 = e0 + 1;
    int ch1 = e1 / 15, p1 = e1 - ch1 * 15;
    float2 ab0 = AB[ch0];
    float2 ab1 = AB[ch1];
    float f0 = bf2f(Yt[p0 * 520 + ch0]);
    float f1 = bf2f(Yt[p1 * 520 + ch1]);
    slab[k * 256 + t] = make_float2(
        fmaxf(fmaf(f0, ab0.x, ab0.y), 0.f),
        fmaxf(fmaf(f1, ab1.x, ab1.y), 0.f));
  }
}

extern "C" void kernel_launch(void* const* d_in, const int* in_sizes, int n_in,
                              void* d_out, int out_size, void* d_ws, size_t ws_size,
                              hipStream_t stream) {
  const float* x = (const float*)d_in[0];
  const float* cw = (const float*)d_in[1];
  // d_in[2] = conv_b: cancelled exactly by training-mode BN -> unused
  const float* gamma = (const float*)d_in[3];
  const float* beta = (const float*)d_in[4];

  unsigned short* wf = (unsigned short*)d_ws;             // 8192*8 bf16 = 128 KB
  float2* Part = (float2*)(wf + 65536);                   // 2048*512 float2 = 8 MB
  float2* AB = Part + (size_t)2048 * 512;                 // 512 float2 = 4 KB

  hipLaunchKernelGGL(k_wprep, dim3(32), dim3(256), 0, stream, cw, wf);
  hipLaunchKernelGGL(k_pass1, dim3(2048), dim3(256), 0, stream, x, wf, Part);
  hipLaunchKernelGGL(k_stats, dim3(64), dim3(256), 0, stream, Part, gamma, beta, AB);
  hipLaunchKernelGGL(k_pass2, dim3(2048), dim3(256), 0, stream, x, wf, AB, (float*)d_out);
}

// Round 12
// 48.409 us; speedup vs baseline: 1.9172x; 1.2942x over previous
//
#include <hip/hip_runtime.h>
#include <hip/hip_bf16.h>
#include <cstdint>

// B=2048, C=256, P=15, channels=512, groups=4 (128 ch each)
// r12 = r7 (best, 48.27us) + x-prefetch folded into k_wprep:
//   pass1's x read was cold (evicted per replay) -> ~9us exposed staging stall.
//   wprep now streams x into L3 (asm-volatile sink) while converting w.
#define EPS_ 1e-5f
#define NVALID_F 30720.0f

typedef __bf16 bf16x8 __attribute__((ext_vector_type(8)));
typedef float f32x16 __attribute__((ext_vector_type(16)));
typedef float f32x4 __attribute__((ext_vector_type(4)));
typedef unsigned short u16x8 __attribute__((ext_vector_type(8)));

__device__ __forceinline__ unsigned short f2bf(float f) {
  unsigned u = __float_as_uint(f);
  u += 0x7FFFu + ((u >> 16) & 1u);   // RNE
  return (unsigned short)(u >> 16);
}
__device__ __forceinline__ float bf2f(unsigned short h) {
  return __uint_as_float((unsigned)h << 16);
}

// ---- prologue: w -> bf16 MFMA B-fragments (blocks 0-31) + x L3-prefetch (all) ----
// Wf[g][mt][ks][lane][j] = w[g][o=mt*32+(lane&31)][i=ks*16+(lane>>5)*8+j]
__global__ __launch_bounds__(256) void k_wprep(const float* __restrict__ w,
                                               unsigned short* __restrict__ wf,
                                               const float* __restrict__ x) {
  const int t = threadIdx.x;
  if (blockIdx.x < 32) {
    int q = blockIdx.x * 256 + t;  // 0..8191
    int l = q & 63, ks = (q >> 6) & 7, mt = (q >> 9) & 3, g = q >> 11;
    int o = mt * 32 + (l & 31);
    int i = ks * 16 + (l >> 5) * 8;
    const float* src = w + ((size_t)(g * 128 + o) * 128 + i);
    u16x8 v;
#pragma unroll
    for (int j = 0; j < 8; ++j) v[j] = f2bf(src[j]);
    *(u16x8*)(wf + (size_t)q * 8) = v;
  }
  // stream all of x (491520 f32x4) into L2/L3; keep loads live via asm sink
  const f32x4* x4 = (const f32x4*)x;
  float acc = 0.f;
  for (int q = blockIdx.x * 256 + t; q < 491520; q += 512 * 256) {
    f32x4 v = x4[q];
    acc += v[0] + v[1] + v[2] + v[3];
  }
  asm volatile("" ::"v"(acc));   // no-DCE sink (rule #17), no store
}

// Build phase shared by both passes: stage 2 x-slabs through Yt union
// (coalesced), then overwrite Yt with bf16 Y = [xs | tmp].
__device__ __forceinline__ void build_Y_union(const float* __restrict__ x, int b0, int t,
                                              unsigned short* __restrict__ Yt) {
  {
    const f32x4* src = (const f32x4*)(x + (size_t)b0 * 3840);
    f32x4* dst = (f32x4*)Yt;
    for (int q = t; q < 1920; q += 256) dst[q] = src[q];
  }
  __syncthreads();
  float v[2][15];
  const float* xsf = (const float*)Yt;
#pragma unroll
  for (int bi = 0; bi < 2; ++bi)
#pragma unroll
    for (int p = 0; p < 15; ++p) v[bi][p] = xsf[bi * 3840 + t * 15 + p];
  __syncthreads();   // all reads done before Yt overwrite
#pragma unroll
  for (int bi = 0; bi < 2; ++bi) {
    float pm[5];
#pragma unroll
    for (int q = 0; q < 5; ++q)
      pm[q] = fmaxf(fmaxf(v[bi][3 * q], v[bi][3 * q + 1]), v[bi][3 * q + 2]);
    float mq[5];
    mq[0] = fmaxf(fmaxf(pm[1], pm[2]), fmaxf(pm[3], pm[4]));
    mq[1] = fmaxf(fmaxf(pm[0], pm[2]), fmaxf(pm[3], pm[4]));
    mq[2] = fmaxf(fmaxf(pm[0], pm[1]), fmaxf(pm[3], pm[4]));
    mq[3] = fmaxf(fmaxf(pm[0], pm[1]), fmaxf(pm[2], pm[4]));
    mq[4] = fmaxf(fmaxf(pm[0], pm[1]), fmaxf(pm[2], pm[3]));
    const int c0 = bi * 16;
#pragma unroll
    for (int p = 0; p < 15; ++p) {
      Yt[(c0 + p) * 520 + t] = f2bf(v[bi][p]);                      // xs -> ch 0..255
      Yt[(c0 + p) * 520 + 256 + t] = f2bf(mq[p / 3] - v[bi][p]);    // tmp -> ch 256..511
    }
    Yt[(c0 + 15) * 520 + t] = 0;        // pad rows: exact 0 (stats unaffected)
    Yt[(c0 + 15) * 520 + 256 + t] = 0;
  }
}

// ---- pass 1: GEMM, per-block (sum,sumsq) partials only ----
__global__ __launch_bounds__(256, 4) void k_pass1(const float* __restrict__ x,
                                                  const unsigned short* __restrict__ wf,
                                                  float2* __restrict__ Part) {
  __shared__ __align__(16) unsigned short Yt[32 * 520];
  const int t = threadIdx.x;
  const int b0 = blockIdx.x * 2;
  build_Y_union(x, b0, t, Yt);
  __syncthreads();

  const int lane = t & 63, g = t >> 6;
  const int l31 = lane & 31, lh = lane >> 5;
  const bf16x8* Wfv = (const bf16x8*)wf;

  bf16x8 bfr[8];
  const unsigned short* yrow = &Yt[l31 * 520 + g * 128 + lh * 8];
#pragma unroll
  for (int ks = 0; ks < 8; ++ks)
    bfr[ks] = *(const bf16x8*)(yrow + ks * 16);

  for (int mt = 0; mt < 4; ++mt) {
    bf16x8 wr[8];
#pragma unroll
    for (int ks = 0; ks < 8; ++ks)
      wr[ks] = Wfv[(size_t)((g * 4 + mt) * 8 + ks) * 64 + lane];
    f32x16 acc;
#pragma unroll
    for (int r = 0; r < 16; ++r) acc[r] = 0.f;
#pragma unroll
    for (int ks = 0; ks < 8; ++ks)
      acc = __builtin_amdgcn_mfma_f32_32x32x16_bf16(bfr[ks], wr[ks], acc, 0, 0, 0);
    float s = 0.f, s2 = 0.f;
#pragma unroll
    for (int r = 0; r < 16; ++r) { float vv = acc[r]; s += vv; s2 = fmaf(vv, vv, s2); }
    s += __shfl_xor(s, 32, 64);
    s2 += __shfl_xor(s2, 32, 64);
    const int ch = g * 128 + mt * 32 + l31;
    if (lane < 32) Part[(size_t)blockIdx.x * 512 + ch] = make_float2(s, s2);
  }
}

// ---- stats: 64 blocks x 8 ch; dense 64B-line reads of Part ----
__global__ void k_stats(const float2* __restrict__ Part,
                        const float* __restrict__ gamma, const float* __restrict__ beta,
                        float2* __restrict__ AB) {
  const int t = threadIdx.x;
  const int chb = blockIdx.x * 8;
  const int c = t & 7, r0 = t >> 3;
  float s = 0.f, s2 = 0.f;
  for (int k = 0; k < 32; ++k) {
    float2 vv = Part[(size_t)(r0 + 32 * k) * 512 + chb + c];
    s += vv.x; s2 += vv.y;
  }
  s += __shfl_xor(s, 8, 64);  s2 += __shfl_xor(s2, 8, 64);
  s += __shfl_xor(s, 16, 64); s2 += __shfl_xor(s2, 16, 64);
  s += __shfl_xor(s, 32, 64); s2 += __shfl_xor(s2, 32, 64);
  __shared__ float2 red[4][8];
  if ((t & 63) < 8) red[t >> 6][c] = make_float2(s, s2);
  __syncthreads();
  if (t < 8) {
    float S = 0.f, S2 = 0.f;
#pragma unroll
    for (int w = 0; w < 4; ++w) { S += red[w][t].x; S2 += red[w][t].y; }
    const float inv = 1.f / NVALID_F;
    float mean = S * inv;
    float var = fmaxf(S2 * inv - mean * mean, 0.f);
    float a = gamma[chb + t] * rsqrtf(var + EPS_);
    AB[chb + t] = make_float2(a, beta[chb + t] - mean * a);
  }
}

// ---- pass 2: recompute GEMM (x L3-hot), z-tile in LDS, finalize ----
__global__ __launch_bounds__(256, 4) void k_pass2(const float* __restrict__ x,
                                                  const unsigned short* __restrict__ wf,
                                                  const float2* __restrict__ AB,
                                                  float* __restrict__ out) {
  __shared__ __align__(16) unsigned short Yt[32 * 520];
  __shared__ float aArr[512], bArr[512];
  const int t = threadIdx.x;
  const int b0 = blockIdx.x * 2;

#pragma unroll
  for (int i = 0; i < 2; ++i) {
    int ch = i * 256 + t;
    float2 ab = AB[ch];
    aArr[ch] = ab.x; bArr[ch] = ab.y;
  }
  build_Y_union(x, b0, t, Yt);
  __syncthreads();

  {
    const int lane = t & 63, g = t >> 6;
    const int l31 = lane & 31, lh = lane >> 5;
    const bf16x8* Wfv = (const bf16x8*)wf;

    bf16x8 bfr[8];
    const unsigned short* yrow = &Yt[l31 * 520 + g * 128 + lh * 8];
#pragma unroll
    for (int ks = 0; ks < 8; ++ks)
      bfr[ks] = *(const bf16x8*)(yrow + ks * 16);

    // wave g reads+writes only cols [g*128, g*128+128): no inter-wave hazard
    for (int mt = 0; mt < 4; ++mt) {
      bf16x8 wr[8];
#pragma unroll
      for (int ks = 0; ks < 8; ++ks)
        wr[ks] = Wfv[(size_t)((g * 4 + mt) * 8 + ks) * 64 + lane];
      f32x16 acc;
#pragma unroll
      for (int r = 0; r < 16; ++r) acc[r] = 0.f;
#pragma unroll
      for (int ks = 0; ks < 8; ++ks)
        acc = __builtin_amdgcn_mfma_f32_32x32x16_bf16(bfr[ks], wr[ks], acc, 0, 0, 0);
      const int ch = g * 128 + mt * 32 + l31;
#pragma unroll
      for (int r = 0; r < 16; ++r) {
        int row = (r & 3) + 8 * (r >> 2) + 4 * lh;
        Yt[row * 520 + ch] = f2bf(acc[r]);   // pad rows written, never read
      }
    }
  }
  __syncthreads();   // z-tile visible to all waves

#pragma unroll
  for (int bi = 0; bi < 2; ++bi) {
    float2* slab = (float2*)(out + (size_t)(b0 + bi) * 7680);
#pragma unroll 5
    for (int k = 0; k < 15; ++k) {
      int e0 = k * 512 + 2 * t;
      int ch0 = e0 / 15, p0 = e0 - ch0 * 15;
      int e1 = e0 + 1;
      int ch1 = e1 / 15, p1 = e1 - ch1 * 15;
      float f0 = bf2f(Yt[(bi * 16 + p0) * 520 + ch0]);
      float f1 = bf2f(Yt[(bi * 16 + p1) * 520 + ch1]);
      slab[k * 256 + t] = make_float2(
          fmaxf(fmaf(f0, aArr[ch0], bArr[ch0]), 0.f),
          fmaxf(fmaf(f1, aArr[ch1], bArr[ch1]), 0.f));
    }
  }
}

extern "C" void kernel_launch(void* const* d_in, const int* in_sizes, int n_in,
                              void* d_out, int out_size, void* d_ws, size_t ws_size,
                              hipStream_t stream) {
  const float* x = (const float*)d_in[0];
  const float* cw = (const float*)d_in[1];
  // d_in[2] = conv_b: cancelled exactly by training-mode BN -> unused
  const float* gamma = (const float*)d_in[3];
  const float* beta = (const float*)d_in[4];

  unsigned short* wf = (unsigned short*)d_ws;             // 8192*8 bf16 = 128 KB
  float2* Part = (float2*)(wf + 65536);                   // 1024*512 float2 = 4 MB
  float2* AB = Part + (size_t)1024 * 512;                 // 512 float2 = 4 KB

  hipLaunchKernelGGL(k_wprep, dim3(512), dim3(256), 0, stream, cw, wf, x);
  hipLaunchKernelGGL(k_pass1, dim3(1024), dim3(256), 0, stream, x, wf, Part);
  hipLaunchKernelGGL(k_stats, dim3(64), dim3(256), 0, stream, Part, gamma, beta, AB);
  hipLaunchKernelGGL(k_pass2, dim3(1024), dim3(256), 0, stream, x, wf, AB, (float*)d_out);
}